// Round 3
// baseline (135.997 us; speedup 1.0000x reference)
//
#include <hip/hip_runtime.h>

// Row-wise dot product: out[n] = sum_d x[n][d] * y[n][d]
// N = 16384 rows, D = 1024 cols, fp32 in / fp32 out.
//
// R6: persistent double-buffered stream (loop + deep MLP, untried combo).
// Evidence ledger so far:
//  - writes: 6.6 TB/s (harness fills). reads: pinned 2.9-3.6 TB/s across
//    NT/cached, 16-32 waves/CU, one-shot burst (R3/R5) and shallow loop
//    (R0-R2). L3-resident == HBM-sourced time (R4 disp 190) -> not HBM-BW,
//    not VALU, not simple-MLP bound.
//  - R5 kernel ~37.6us (graded 134.0 - 96.4us fixed fills) = 3.57 TB/s.
// Hypothesis under test: one-shot blocks create duty-cycle gaps (drain ->
// compute tail -> retire -> relaunch, ~5-8 generations/CU). This kernel
// keeps the read queues continuously full: each wave owns 8 rows, processed
// as 4 iterations of 2 rows with register double-buffering -- the next
// iteration's 16 nontemporal loads are issued BEFORE the current buffer is
// consumed, so the request stream never drains until the epilogue.
// Grid: 512 blocks x 256 thr = 2048 waves (2 blocks/CU resident, 8 waves/CU;
// in-flight ~128KB/CU >> ~10KB needed for latency coverage).
// If this does NOT beat ~37.5us kernel / ~134 graded, the ~3.5 TB/s read
// cap is structural (request-path/fabric) and we are at the roofline.

#define D 1024

typedef float v4f __attribute__((ext_vector_type(4)));

__device__ __forceinline__ float dot4(v4f a, v4f b) {
    return a.x * b.x + a.y * b.y + a.z * b.z + a.w * b.w;
}

__global__ __launch_bounds__(256) void rowdot_kernel(const float* __restrict__ x,
                                                     const float* __restrict__ y,
                                                     float* __restrict__ out) {
    const int wave = threadIdx.x >> 6;
    const int lane = threadIdx.x & 63;
    const int w = blockIdx.x * 4 + wave;   // global wave id, 0..2047
    const int row0 = w * 8;                // this wave owns rows [row0, row0+8)

    // v4f row stride = D/4 = 256; each row is 4 chunks of 64 lanes.
    const v4f* __restrict__ xp = (const v4f*)(x + (size_t)row0 * D);
    const v4f* __restrict__ yp = (const v4f*)(y + (size_t)row0 * D);

    v4f bufA[16], bufB[16];

    // Issue 16 independent NT loads for row-pair r (rows 2r, 2r+1) into buf.
    // r is compile-time constant at every call site; all indices static.
    auto issue = [&](v4f(&buf)[16], const int r) {
#pragma unroll
        for (int j = 0; j < 4; ++j) {
            buf[j]      = __builtin_nontemporal_load(&xp[(2 * r) * 256 + j * 64 + lane]);
            buf[4 + j]  = __builtin_nontemporal_load(&yp[(2 * r) * 256 + j * 64 + lane]);
            buf[8 + j]  = __builtin_nontemporal_load(&xp[(2 * r + 1) * 256 + j * 64 + lane]);
            buf[12 + j] = __builtin_nontemporal_load(&yp[(2 * r + 1) * 256 + j * 64 + lane]);
        }
    };

    // Consume buf: two dot products + two interleaved wave-64 reductions.
    auto consume = [&](v4f(&buf)[16], const int r) {
        float s0 = 0.0f, s1 = 0.0f;
#pragma unroll
        for (int j = 0; j < 4; ++j) {
            s0 += dot4(buf[j], buf[4 + j]);
            s1 += dot4(buf[8 + j], buf[12 + j]);
        }
#pragma unroll
        for (int off = 32; off > 0; off >>= 1) {
            s0 += __shfl_down(s0, off, 64);
            s1 += __shfl_down(s1, off, 64);
        }
        if (lane == 0) {
            *(float2*)(out + row0 + 2 * r) = make_float2(s0, s1);
        }
    };

    // Software pipeline: next iteration's loads are in flight before the
    // current buffer is consumed. asm barriers pin issue order.
    issue(bufA, 0);
    asm volatile("" ::: "memory");
    issue(bufB, 1);
    asm volatile("" ::: "memory");
    consume(bufA, 0);
    issue(bufA, 2);
    asm volatile("" ::: "memory");
    consume(bufB, 1);
    issue(bufB, 3);
    asm volatile("" ::: "memory");
    consume(bufA, 2);
    consume(bufB, 3);
}

extern "C" void kernel_launch(void* const* d_in, const int* in_sizes, int n_in,
                              void* d_out, int out_size, void* d_ws, size_t ws_size,
                              hipStream_t stream) {
    const float* x = (const float*)d_in[0];
    const float* y = (const float*)d_in[1];
    float* out = (float*)d_out;
    const int N = out_size;  // 16384 rows

    // 8 rows per wave, 4 waves per block -> 32 rows per block
    // grid = 512 blocks = 2 blocks/CU, persistent (no relaunch churn)
    rowdot_kernel<<<N / 32, 256, 0, stream>>>(x, y, out);
}

// Round 4
// 134.695 us; speedup vs baseline: 1.0097x; 1.0097x over previous
//
#include <hip/hip_runtime.h>

// Row-wise dot product: out[n] = sum_d x[n][d] * y[n][d]
// N = 16384 rows, D = 1024 cols, fp32 in / fp32 out.
//
// R7: revert to the proven-best R5 structure (R6's persistent double-buffer
// regressed 134.0 -> 136.0).
// Final evidence ledger (7 structural variants):
//  - writes: 6.6 TB/s (harness 256MiB fills, same chip/session).
//  - reads: pinned 2.9-3.6 TB/s across NT/cached, 16-32 waves/CU, one-shot
//    burst, shallow loop, and persistent double-buffered streams.
//  - L3-resident reads == HBM-sourced reads (R4 disp 190: hbm_bytes=66KB,
//    45.7us == 46.4us with 67MB fetched) -> cap is the XCD-inbound read
//    path, not the memory source.
//  - Best: THIS structure (R3/R5, twice): ~37.6us kernel = 3.57 TB/s.
// Roofline arithmetic: 134.2 MB mandatory reads (each element consumed
// exactly once -- minimal traffic) / 3.57 TB/s measured read ceiling
// = 37.6us kernel floor, achieved. Graded = kernel + ~96.4us fixed
// harness fills = ~134us.
//
// Structure: 2 rows/wave, 4 waves/block, grid=N/8=2048 blocks (8 blocks/CU,
// 32 waves/CU, full occupancy), 16 independent nontemporal 16B loads
// clustered before a compiler barrier so all are in flight before the
// first consumer; s_waitcnt drains progressively in issue order.

#define D 1024

typedef float v4f __attribute__((ext_vector_type(4)));

__global__ __launch_bounds__(256) void rowdot_kernel(const float* __restrict__ x,
                                                     const float* __restrict__ y,
                                                     float* __restrict__ out) {
    const int wave = threadIdx.x >> 6;
    const int lane = threadIdx.x & 63;
    const int w = blockIdx.x * 4 + wave;  // global wave id
    const int r0 = w * 2;                 // two consecutive rows per wave

    const v4f* __restrict__ x0 = (const v4f*)(x + (size_t)r0 * D);
    const v4f* __restrict__ y0 = (const v4f*)(y + (size_t)r0 * D);
    const v4f* __restrict__ x1 = (const v4f*)(x + (size_t)(r0 + 1) * D);
    const v4f* __restrict__ y1 = (const v4f*)(y + (size_t)(r0 + 1) * D);

    // 16 independent loads, pinned before any use by the barrier below.
    v4f a0 = __builtin_nontemporal_load(&x0[lane]);
    v4f a1 = __builtin_nontemporal_load(&x0[lane + 64]);
    v4f a2 = __builtin_nontemporal_load(&x0[lane + 128]);
    v4f a3 = __builtin_nontemporal_load(&x0[lane + 192]);
    v4f b0 = __builtin_nontemporal_load(&y0[lane]);
    v4f b1 = __builtin_nontemporal_load(&y0[lane + 64]);
    v4f b2 = __builtin_nontemporal_load(&y0[lane + 128]);
    v4f b3 = __builtin_nontemporal_load(&y0[lane + 192]);
    v4f c0 = __builtin_nontemporal_load(&x1[lane]);
    v4f c1 = __builtin_nontemporal_load(&x1[lane + 64]);
    v4f c2 = __builtin_nontemporal_load(&x1[lane + 128]);
    v4f c3 = __builtin_nontemporal_load(&x1[lane + 192]);
    v4f d0 = __builtin_nontemporal_load(&y1[lane]);
    v4f d1 = __builtin_nontemporal_load(&y1[lane + 64]);
    v4f d2 = __builtin_nontemporal_load(&y1[lane + 128]);
    v4f d3 = __builtin_nontemporal_load(&y1[lane + 192]);

    // Compiler barrier: all 16 loads must be issued before anything below.
    asm volatile("" ::: "memory");

    float s0 = 0.0f, s1 = 0.0f;
    s0 += a0.x * b0.x + a0.y * b0.y + a0.z * b0.z + a0.w * b0.w;
    s0 += a1.x * b1.x + a1.y * b1.y + a1.z * b1.z + a1.w * b1.w;
    s0 += a2.x * b2.x + a2.y * b2.y + a2.z * b2.z + a2.w * b2.w;
    s0 += a3.x * b3.x + a3.y * b3.y + a3.z * b3.z + a3.w * b3.w;
    s1 += c0.x * d0.x + c0.y * d0.y + c0.z * d0.z + c0.w * d0.w;
    s1 += c1.x * d1.x + c1.y * d1.y + c1.z * d1.z + c1.w * d1.w;
    s1 += c2.x * d2.x + c2.y * d2.y + c2.z * d2.z + c2.w * d2.w;
    s1 += c3.x * d3.x + c3.y * d3.y + c3.z * d3.z + c3.w * d3.w;

    // two interleaved wave-64 reduction chains
    #pragma unroll
    for (int off = 32; off > 0; off >>= 1) {
        s0 += __shfl_down(s0, off, 64);
        s1 += __shfl_down(s1, off, 64);
    }

    if (lane == 0) {
        *(float2*)(out + r0) = make_float2(s0, s1);
    }
}

extern "C" void kernel_launch(void* const* d_in, const int* in_sizes, int n_in,
                              void* d_out, int out_size, void* d_ws, size_t ws_size,
                              hipStream_t stream) {
    const float* x = (const float*)d_in[0];
    const float* y = (const float*)d_in[1];
    float* out = (float*)d_out;
    const int N = out_size;  // 16384 rows

    // 2 rows per wave, 4 waves per block -> 8 rows per block
    // grid = 2048 blocks = 8 blocks/CU = 32 waves/CU (full occupancy)
    rowdot_kernel<<<N / 8, 256, 0, stream>>>(x, y, out);
}